// Round 2
// baseline (964.017 us; speedup 1.0000x reference)
//
#include <hip/hip_runtime.h>

#define B_ 4
#define C_ 64
#define F_ 128
#define T_ 128
#define K_ 8
#define H_ 32
#define S_ 121   // T - K + 1
#define N_ 512   // B * F
#define G_ 128   // 4 * H
#define CK_ 512  // C * K

__device__ __forceinline__ float sigm(float x){ return 1.f/(1.f + __expf(-x)); }
__device__ __forceinline__ float tanhx(float x){ return 1.f - 2.f/(__expf(2.f*x)+1.f); }

// ---------------------------------------------------------------- instance norm stats
__global__ __launch_bounds__(256) void k_norm(const float* __restrict__ x,
    const float* __restrict__ gamma, const float* __restrict__ beta,
    float* __restrict__ scale, float* __restrict__ shift){
  int bc = blockIdx.x;                       // b*C + c
  const float* p = x + (size_t)bc * (F_*T_);
  float s = 0.f, q = 0.f;
  for (int i = threadIdx.x; i < F_*T_; i += 256){ float v = p[i]; s += v; q += v*v; }
  #pragma unroll
  for (int o = 32; o; o >>= 1){ s += __shfl_down(s, o); q += __shfl_down(q, o); }
  __shared__ float ss[4], qq[4];
  int w = threadIdx.x >> 6;
  if ((threadIdx.x & 63) == 0){ ss[w] = s; qq[w] = q; }
  __syncthreads();
  if (threadIdx.x == 0){
    s = ss[0]+ss[1]+ss[2]+ss[3]; q = qq[0]+qq[1]+qq[2]+qq[3];
    float mu  = s / (float)(F_*T_);
    float var = q / (float)(F_*T_) - mu*mu;
    if (var < 0.f) var = 0.f;
    int c = bc & (C_-1);
    float sc = gamma[c] * rsqrtf(var + 1e-5f);
    scale[bc] = sc;
    shift[bc] = beta[c] - mu * sc;
  }
}

// ---------------------------------------------------------------- layer-0 input projection
// gx[d][s][n][g] = sum_{c,k} xn[n][c][s+k] * w0[d][g][c*8+k] + bi[d][g] + bh[d][g]
__global__ __launch_bounds__(256) void k_gx0(const float* __restrict__ x,
    const float* __restrict__ scale, const float* __restrict__ shift,
    const float* __restrict__ w0, const float* __restrict__ bi,
    const float* __restrict__ bh, float* __restrict__ gx){
  __shared__ float xs[C_][140];              // cols 128..139 are zero halo
  int n = blockIdx.x, b = n >> 7, f = n & 127;
  for (int i = threadIdx.x; i < C_*12; i += 256)
    xs[i/12][128 + i%12] = 0.f;
  const float* xb = x + (size_t)b*C_*F_*T_ + (size_t)f*T_;
  for (int i = threadIdx.x; i < C_*T_; i += 256){
    int c = i >> 7, t = i & 127;
    xs[c][t] = xb[(size_t)c*F_*T_ + t] * scale[b*C_+c] + shift[b*C_+c];
  }
  __syncthreads();
  int d = threadIdx.x >> 7, g = threadIdx.x & 127;
  const float* wr = w0 + (size_t)(d*G_+g)*CK_;
  float bias = bi[d*G_+g] + bh[d*G_+g];
  for (int st = 0; st < 4; ++st){
    int s0 = st * 32;
    float acc[32];
    #pragma unroll
    for (int s = 0; s < 32; ++s) acc[s] = bias;
    for (int c = 0; c < C_; ++c){
      float4 wa = *(const float4*)(wr + c*8);
      float4 wb = *(const float4*)(wr + c*8 + 4);
      float wv[8] = {wa.x,wa.y,wa.z,wa.w,wb.x,wb.y,wb.z,wb.w};
      float xv[39];
      #pragma unroll
      for (int j = 0; j < 39; ++j) xv[j] = xs[c][s0+j];   // wave-uniform: broadcast
      #pragma unroll
      for (int k = 0; k < 8; ++k)
        #pragma unroll
        for (int s = 0; s < 32; ++s)
          acc[s] += xv[s+k] * wv[k];
    }
    int smax = S_ - s0; if (smax > 32) smax = 32;
    for (int s = 0; s < smax; ++s)
      gx[((size_t)(d*S_ + s0+s)*N_ + n)*G_ + g] = acc[s];
  }
}

// ---------------------------------------------------------------- layers 1..3 input projection
// gx[d][s][n][g] = sum_{i<64} h[s][n][i] * wl[d][g][i] + bi[d][g] + bh[d][g]
__global__ __launch_bounds__(256) void k_gxl(const float* __restrict__ hin,
    const float* __restrict__ wl, const float* __restrict__ bi,
    const float* __restrict__ bh, float* __restrict__ gx){
  __shared__ float hT[64][129];              // pad 129: staging writes conflict-free
  int n = blockIdx.x;
  for (int i = threadIdx.x; i < 64*8; i += 256)
    hT[i >> 3][121 + (i & 7)] = 0.f;
  for (int i = threadIdx.x; i < S_*64; i += 256){
    int s = i >> 6, ci = i & 63;
    hT[ci][s] = hin[((size_t)s*N_ + n)*64 + ci];
  }
  __syncthreads();
  int d = threadIdx.x >> 7, g = threadIdx.x & 127;
  const float* wr = wl + (size_t)(d*G_+g)*64;
  float bias = bi[d*G_+g] + bh[d*G_+g];
  for (int st = 0; st < 4; ++st){
    int s0 = st * 32;
    float acc[32];
    #pragma unroll
    for (int s = 0; s < 32; ++s) acc[s] = bias;
    for (int i4 = 0; i4 < 16; ++i4){
      float4 wv = *(const float4*)(wr + i4*4);
      float wq[4] = {wv.x, wv.y, wv.z, wv.w};
      #pragma unroll
      for (int ii = 0; ii < 4; ++ii){
        int i = i4*4 + ii;
        #pragma unroll
        for (int s = 0; s < 32; ++s)
          acc[s] += hT[i][s0+s] * wq[ii];    // wave-uniform: broadcast
      }
    }
    int smax = S_ - s0; if (smax > 32) smax = 32;
    for (int s = 0; s < smax; ++s)
      gx[((size_t)(d*S_ + s0+s)*N_ + n)*G_ + g] = acc[s];
  }
}

// ---------------------------------------------------------------- LSTM recurrence
// one block per (n, dir); 128 threads = 128 gate rows; 2-deep gx prefetch
__global__ __launch_bounds__(128) void k_lstm(const float* __restrict__ gx,
    const float* __restrict__ whh, float* __restrict__ hout){
  int blk = blockIdx.x;
  int n = blk & (N_-1), d = blk >> 9;
  int g = threadIdx.x;
  float w[32];
  const float* wr = whh + (size_t)(d*G_+g)*H_;
  #pragma unroll
  for (int j = 0; j < 32; ++j) w[j] = wr[j];
  __shared__ float hl[32];
  __shared__ float gl[128];
  float c = 0.f;
  if (g < 32) hl[g] = 0.f;
  __syncthreads();

  auto gidx = [&](int st) -> size_t {
    int s = d ? (S_-1-st) : st;
    return ((size_t)(d*S_ + s)*N_ + n)*G_ + g;
  };
  auto body = [&](int st, float acc){
    #pragma unroll
    for (int j = 0; j < 32; ++j) acc += hl[j] * w[j];
    __syncthreads();
    gl[g] = acc;
    __syncthreads();
    if (g < 32){
      float ig = sigm (gl[g]);
      float fg = sigm (gl[32+g]);
      float gg = tanhx(gl[64+g]);
      float og = sigm (gl[96+g]);
      c = fg*c + ig*gg;
      float h = og * tanhx(c);
      hl[g] = h;
      int s = d ? (S_-1-st) : st;
      hout[((size_t)s*N_ + n)*64 + d*32 + g] = h;
    }
    __syncthreads();
  };

  float p0 = gx[gidx(0)];
  float p1 = gx[gidx(1)];
  for (int st = 0; st < S_; st += 2){
    {
      float acc = p0;
      p0 = (st+2 < S_) ? gx[gidx(st+2)] : 0.f;
      body(st, acc);
    }
    if (st+1 < S_){                          // uniform branch: barrier-safe
      float acc = p1;
      p1 = (st+3 < S_) ? gx[gidx(st+3)] : 0.f;
      body(st+1, acc);
    }
  }
}

// ---------------------------------------------------------------- ConvTranspose (reference semantics)
// jax conv_transpose('IOH', transpose_kernel=True) computes
//   y[n, co, t] = sum_{ci,k} h[n, ci, t-k] * wct[co, ci, k]
// i.e. output channel indexes wct AXIS 0 (2H), contraction over AXIS 1 (C).
__global__ __launch_bounds__(256) void k_conv(const float* __restrict__ hin,
    const float* __restrict__ wct, const float* __restrict__ bct,
    const float* __restrict__ x, float* __restrict__ out){
  __shared__ float hT[64][137];              // [ci][s+8], zero halo both sides
  int n = blockIdx.x, b = n >> 7, f = n & 127;
  for (int i = threadIdx.x; i < 64*16; i += 256){
    int ci = i >> 4, j = i & 15;
    hT[ci][j < 8 ? j : (121 + j)] = 0.f;     // cols 0..7 and 129..136
  }
  for (int i = threadIdx.x; i < S_*64; i += 256){
    int s = i >> 6, ci = i & 63;
    hT[ci][s+8] = hin[((size_t)s*N_ + n)*64 + ci];
  }
  __syncthreads();
  int co = threadIdx.x >> 2, t0 = (threadIdx.x & 3) * 32;
  float acc[32];
  #pragma unroll
  for (int s = 0; s < 32; ++s) acc[s] = 0.f;
  for (int ci = 0; ci < 64; ++ci){
    const float* wr = wct + (size_t)(co*64 + ci)*8;   // [co][ci][k] — axis-swapped per jax semantics
    float4 wa = *(const float4*)(wr);
    float4 wb = *(const float4*)(wr + 4);
    float wv[8] = {wa.x,wa.y,wa.z,wa.w,wb.x,wb.y,wb.z,wb.w};
    float hv[40];
    #pragma unroll
    for (int j = 0; j < 40; ++j) hv[j] = hT[ci][t0+j];
    #pragma unroll
    for (int k = 0; k < 8; ++k)
      #pragma unroll
      for (int s = 0; s < 32; ++s)
        acc[s] += hv[s+8-k] * wv[k];         // y[t]=sum_k h[t-k]*w[k], halo handles edges
  }
  size_t base = ((size_t)(b*64 + co)*128 + f)*128 + t0;
  float bias = bct[co];
  #pragma unroll
  for (int s = 0; s < 32; ++s)
    out[base + s] = acc[s] + bias + x[base + s];
}

// ----------------------------------------------------------------
extern "C" void kernel_launch(void* const* d_in, const int* in_sizes, int n_in,
                              void* d_out, int out_size, void* d_ws, size_t ws_size,
                              hipStream_t stream){
  const float* x     = (const float*)d_in[0];
  const float* gamma = (const float*)d_in[1];
  const float* beta  = (const float*)d_in[2];
  const float* wih0  = (const float*)d_in[3];   // [2,128,512]
  const float* whh0  = (const float*)d_in[4];   // [2,128,32]
  const float* bih0  = (const float*)d_in[5];   // [2,128]
  const float* bhh0  = (const float*)d_in[6];   // [2,128]
  const float* wih   = (const float*)d_in[7];   // [3,2,128,64]
  const float* whh   = (const float*)d_in[8];   // [3,2,128,32]
  const float* bih   = (const float*)d_in[9];   // [3,2,128]
  const float* bhh   = (const float*)d_in[10];  // [3,2,128]
  const float* wct   = (const float*)d_in[11];  // [64,64,8]
  const float* bct   = (const float*)d_in[12];  // [64]
  float* out = (float*)d_out;

  float* wsf   = (float*)d_ws;
  float* scale = wsf;                            // 256
  float* shift = wsf + 256;                      // 256
  float* gx    = wsf + 512;                      // 2*121*512*128 = 15,859,712
  float* hA    = gx + (size_t)2*S_*N_*G_;        // 121*512*64 = 3,964,928
  float* hB    = hA + (size_t)S_*N_*64;          // total ~95.2 MB

  k_norm<<<256, 256, 0, stream>>>(x, gamma, beta, scale, shift);
  k_gx0 <<<512, 256, 0, stream>>>(x, scale, shift, wih0, bih0, bhh0, gx);
  k_lstm<<<1024, 128, 0, stream>>>(gx, whh0, hA);
  float* hp = hA; float* hn = hB;
  for (int l = 0; l < 3; ++l){
    k_gxl <<<512, 256, 0, stream>>>(hp, wih + (size_t)l*2*G_*64,
                                    bih + (size_t)l*2*G_, bhh + (size_t)l*2*G_, gx);
    k_lstm<<<1024, 128, 0, stream>>>(gx, whh + (size_t)l*2*G_*H_, hn);
    float* tmp = hp; hp = hn; hn = tmp;
  }
  k_conv<<<512, 256, 0, stream>>>(hp, wct, bct, x, out);
}

// Round 3
// 577.103 us; speedup vs baseline: 1.6704x; 1.6704x over previous
//
#include <hip/hip_runtime.h>

#define B_ 4
#define C_ 64
#define F_ 128
#define T_ 128
#define K_ 8
#define H_ 32
#define S_ 121   // T - K + 1
#define N_ 512   // B * F
#define G_ 128   // 4 * H
#define CK_ 512  // C * K

typedef __attribute__((ext_vector_type(8))) short short8;
typedef __attribute__((ext_vector_type(4))) float f32x4;
union FragU { uint4 u; short8 s; };

__device__ __forceinline__ unsigned int pk2(float a, float b){   // RNE f32->bf16 pair
  unsigned int ua = __float_as_uint(a); ua += 0x7fffu + ((ua>>16)&1u);
  unsigned int ub = __float_as_uint(b); ub += 0x7fffu + ((ub>>16)&1u);
  return (ua>>16) | (ub & 0xffff0000u);
}
__device__ __forceinline__ unsigned short bfu(float a){          // RNE f32->bf16
  unsigned int ua = __float_as_uint(a); ua += 0x7fffu + ((ua>>16)&1u);
  return (unsigned short)(ua>>16);
}
__device__ __forceinline__ float ubf(unsigned short v){
  return __uint_as_float(((unsigned int)v) << 16);
}

// ---------------------------------------------------------------- instance norm stats
__global__ __launch_bounds__(256) void k_norm(const float* __restrict__ x,
    const float* __restrict__ gamma, const float* __restrict__ beta,
    float* __restrict__ scale, float* __restrict__ shift){
  int bc = blockIdx.x;
  const float* p = x + (size_t)bc * (F_*T_);
  float s = 0.f, q = 0.f;
  for (int i = threadIdx.x; i < F_*T_; i += 256){ float v = p[i]; s += v; q += v*v; }
  #pragma unroll
  for (int o = 32; o; o >>= 1){ s += __shfl_down(s, o); q += __shfl_down(q, o); }
  __shared__ float ss[4], qq[4];
  int w = threadIdx.x >> 6;
  if ((threadIdx.x & 63) == 0){ ss[w] = s; qq[w] = q; }
  __syncthreads();
  if (threadIdx.x == 0){
    s = ss[0]+ss[1]+ss[2]+ss[3]; q = qq[0]+qq[1]+qq[2]+qq[3];
    float mu  = s / (float)(F_*T_);
    float var = q / (float)(F_*T_) - mu*mu;
    if (var < 0.f) var = 0.f;
    int c = bc & (C_-1);
    float sc = gamma[c] * rsqrtf(var + 1e-5f);
    scale[bc] = sc;
    shift[bc] = beta[c] - mu * sc;
  }
}

// ---------------------------------------------------------------- weight f32 -> bf16
__global__ __launch_bounds__(256) void k_wcvt(const float* __restrict__ a,
    unsigned short* __restrict__ o, int nel){
  int i = blockIdx.x*256 + threadIdx.x;
  if (i < nel) o[i] = bfu(a[i]);
}

// ---------------------------------------------------------------- layer-0 projection, MFMA bf16
// gx[d][s][n][g] = sum_{c,k} xn[n][c][s+k] * w0[d][g][ck] + bias   (per-n block)
__global__ __launch_bounds__(256) void k_gx0(const float* __restrict__ x,
    const float* __restrict__ scale, const float* __restrict__ shift,
    const unsigned short* __restrict__ wb0, const float* __restrict__ bi,
    const float* __restrict__ bh, unsigned short* __restrict__ gx){
  __shared__ unsigned int xsp[C_][136];     // packed bf16 pairs (t, t+1); t>=128 zero
  int n = blockIdx.x, b = n >> 7, f = n & 127;
  const float* xb = x + (size_t)b*C_*F_*T_ + (size_t)f*T_;
  for (int i = threadIdx.x; i < C_*136; i += 256){
    int c = i / 136, t = i - c*136;
    float sc = scale[b*C_+c], sh = shift[b*C_+c];
    float v0 = (t   < T_) ? xb[(size_t)c*F_*T_ + t  ]*sc + sh : 0.f;
    float v1 = (t+1 < T_) ? xb[(size_t)c*F_*T_ + t+1]*sc + sh : 0.f;
    xsp[c][t] = pk2(v0, v1);
  }
  __syncthreads();
  int lane = threadIdx.x & 63, wv = threadIdx.x >> 6;
  int ln = lane & 15, quad = lane >> 4;
  int g256[4]; f32x4 acc[8][4];
  #pragma unroll
  for (int gi = 0; gi < 4; ++gi){
    g256[gi] = (wv*4 + gi)*16 + ln;
    float bv = bi[g256[gi]] + bh[g256[gi]];
    #pragma unroll
    for (int st = 0; st < 8; ++st) acc[st][gi] = (f32x4){bv, bv, bv, bv};
  }
  for (int kb = 0; kb < 16; ++kb){
    FragU bfr[4];
    #pragma unroll
    for (int gi = 0; gi < 4; ++gi)
      bfr[gi].u = *(const uint4*)(wb0 + (size_t)g256[gi]*CK_ + kb*32 + quad*8);
    #pragma unroll
    for (int st = 0; st < 8; ++st){
      FragU a;
      const unsigned int* rp = &xsp[kb*4 + quad][st*16 + ln];
      a.u.x = rp[0]; a.u.y = rp[2]; a.u.z = rp[4]; a.u.w = rp[6];
      #pragma unroll
      for (int gi = 0; gi < 4; ++gi)
        acc[st][gi] = __builtin_amdgcn_mfma_f32_16x16x32_bf16(a.s, bfr[gi].s, acc[st][gi], 0, 0, 0);
    }
  }
  #pragma unroll
  for (int st = 0; st < 8; ++st)
    #pragma unroll
    for (int gi = 0; gi < 4; ++gi){
      int d = g256[gi] >> 7, g = g256[gi] & 127;
      #pragma unroll
      for (int r = 0; r < 4; ++r){
        int s = st*16 + quad*4 + r;
        if (s < S_)
          gx[((size_t)(d*S_ + s)*N_ + n)*G_ + g] = bfu(acc[st][gi][r]);
      }
    }
}

// ---------------------------------------------------------------- layers 1..3 projection, MFMA bf16
__global__ __launch_bounds__(256) void k_gxl(const unsigned short* __restrict__ hin,
    const unsigned short* __restrict__ wlb, const float* __restrict__ bi,
    const float* __restrict__ bh, unsigned short* __restrict__ gx){
  __shared__ unsigned int hsp[32][132];     // [i_pair][s], s>=121 zero
  int n = blockIdx.x;
  const unsigned int* hu = (const unsigned int*)hin;
  for (int i = threadIdx.x; i < 32*128; i += 256){
    int s = i >> 5, ip = i & 31;
    hsp[ip][s] = (s < S_) ? hu[((size_t)s*N_ + n)*32 + ip] : 0u;
  }
  __syncthreads();
  int lane = threadIdx.x & 63, wv = threadIdx.x >> 6;
  int ln = lane & 15, quad = lane >> 4;
  int g256[4]; f32x4 acc[8][4];
  #pragma unroll
  for (int gi = 0; gi < 4; ++gi){
    g256[gi] = (wv*4 + gi)*16 + ln;
    float bv = bi[g256[gi]] + bh[g256[gi]];
    #pragma unroll
    for (int st = 0; st < 8; ++st) acc[st][gi] = (f32x4){bv, bv, bv, bv};
  }
  #pragma unroll
  for (int kb = 0; kb < 2; ++kb){
    FragU bfr[4];
    #pragma unroll
    for (int gi = 0; gi < 4; ++gi)
      bfr[gi].u = *(const uint4*)(wlb + (size_t)g256[gi]*64 + kb*32 + quad*8);
    #pragma unroll
    for (int st = 0; st < 8; ++st){
      FragU a;
      int ipb = kb*16 + quad*4, srow = st*16 + ln;
      a.u.x = hsp[ipb+0][srow]; a.u.y = hsp[ipb+1][srow];
      a.u.z = hsp[ipb+2][srow]; a.u.w = hsp[ipb+3][srow];
      #pragma unroll
      for (int gi = 0; gi < 4; ++gi)
        acc[st][gi] = __builtin_amdgcn_mfma_f32_16x16x32_bf16(a.s, bfr[gi].s, acc[st][gi], 0, 0, 0);
    }
  }
  #pragma unroll
  for (int st = 0; st < 8; ++st)
    #pragma unroll
    for (int gi = 0; gi < 4; ++gi){
      int d = g256[gi] >> 7, g = g256[gi] & 127;
      #pragma unroll
      for (int r = 0; r < 4; ++r){
        int s = st*16 + quad*4 + r;
        if (s < S_)
          gx[((size_t)(d*S_ + s)*N_ + n)*G_ + g] = bfu(acc[st][gi][r]);
      }
    }
}

// ---------------------------------------------------------------- LSTM: one wave per (n,dir), no barriers
__global__ __launch_bounds__(64) void k_lstm(const unsigned short* __restrict__ gx,
    const float* __restrict__ whh, unsigned short* __restrict__ hout){
  int blk = blockIdx.x;
  int n = blk & (N_-1), d = blk >> 9;
  int lane = threadIdx.x;
  int j = lane & 31, hi = lane >> 5;
  int r1 = lane;            // rows: lanes 0-31 -> i_j ; lanes 32-63 -> f_j
  int r2 = lane + 64;       //        lanes 0-31 -> g_j ; lanes 32-63 -> o_j
  float w1[32], w2[32];
  const float* wr1 = whh + (size_t)(d*G_ + r1)*H_;
  const float* wr2 = whh + (size_t)(d*G_ + r2)*H_;
  #pragma unroll
  for (int q = 0; q < 8; ++q){
    float4 aa = *(const float4*)(wr1 + q*4);
    float4 bb = *(const float4*)(wr2 + q*4);
    w1[q*4+0]=aa.x; w1[q*4+1]=aa.y; w1[q*4+2]=aa.z; w1[q*4+3]=aa.w;
    w2[q*4+0]=bb.x; w2[q*4+1]=bb.y; w2[q*4+2]=bb.z; w2[q*4+3]=bb.w;
  }
  unsigned short q1[4], q2[4];
  auto gp = [&](int st)->const unsigned short*{
    int s = d ? (S_-1-st) : st;
    return gx + ((size_t)(d*S_ + s)*N_ + n)*G_;
  };
  #pragma unroll
  for (int u = 0; u < 4; ++u){ const unsigned short* p = gp(u); q1[u] = p[r1]; q2[u] = p[r2]; }
  float hv = 0.f, c = 0.f;
  for (int stb = 0; stb < 31; ++stb){
    #pragma unroll
    for (int u = 0; u < 4; ++u){
      int st = stb*4 + u;
      if (st >= S_) break;                       // wave-uniform
      float acc1 = ubf(q1[u]), acc2 = ubf(q2[u]);
      int pf = st + 4; if (pf > S_-1) pf = S_-1; // clamped overfetch, value unused
      const unsigned short* pp = gp(pf);
      q1[u] = pp[r1]; q2[u] = pp[r2];
      float s1 = acc1, s2 = 0.f, s3 = acc2, s4 = 0.f;
      #pragma unroll
      for (int k = 0; k < 32; k += 2){
        float ha = __uint_as_float(__builtin_amdgcn_readlane(__float_as_uint(hv), k));
        float hb = __uint_as_float(__builtin_amdgcn_readlane(__float_as_uint(hv), k+1));
        s1 += ha*w1[k]; s2 += hb*w1[k+1];
        s3 += ha*w2[k]; s4 += hb*w2[k+1];
      }
      acc1 = s1 + s2; acc2 = s3 + s4;
      float a1 = 1.f/(1.f + __expf(-acc1));            // sigmoid (i or f)
      float x2 = hi ? acc2 : 2.f*acc2;                 // shared-exp: o sigm / g tanh
      float tt = 1.f/(1.f + __expf(-x2));
      float a2 = hi ? tt : 2.f*tt - 1.f;
      float b1 = __shfl_xor(a1, 32);
      float b2 = __shfl_xor(a2, 32);
      float i_ = hi ? b1 : a1;
      float f_ = hi ? a1 : b1;
      float g_ = hi ? b2 : a2;
      float o_ = hi ? a2 : b2;
      c = f_*c + i_*g_;
      float tc = 1.f/(1.f + __expf(-2.f*c));
      hv = o_*(2.f*tc - 1.f);
      if (!hi){
        int s = d ? (S_-1-st) : st;
        hout[((size_t)s*N_ + n)*64 + d*32 + j] = bfu(hv);
      }
    }
  }
}

// ---------------------------------------------------------------- ConvTranspose (jax semantics) + residual
// y[n, co, t] = sum_{ci,k} h[n, ci, t-k] * wct[co, ci, k]
__global__ __launch_bounds__(256) void k_conv(const unsigned short* __restrict__ hin,
    const float* __restrict__ wct, const float* __restrict__ bct,
    const float* __restrict__ x, float* __restrict__ out){
  __shared__ float hT[64][137];
  int n = blockIdx.x, b = n >> 7, f = n & 127;
  for (int i = threadIdx.x; i < 64*16; i += 256){
    int ci = i >> 4, jj = i & 15;
    hT[ci][jj < 8 ? jj : (121 + jj)] = 0.f;
  }
  for (int i = threadIdx.x; i < S_*64; i += 256){
    int s = i >> 6, ci = i & 63;
    hT[ci][s+8] = ubf(hin[((size_t)s*N_ + n)*64 + ci]);
  }
  __syncthreads();
  int co = threadIdx.x >> 2, t0 = (threadIdx.x & 3) * 32;
  float acc[32];
  #pragma unroll
  for (int s = 0; s < 32; ++s) acc[s] = 0.f;
  for (int ci = 0; ci < 64; ++ci){
    const float* wr = wct + (size_t)(co*64 + ci)*8;
    float4 wa = *(const float4*)(wr);
    float4 wb = *(const float4*)(wr + 4);
    float wv[8] = {wa.x,wa.y,wa.z,wa.w,wb.x,wb.y,wb.z,wb.w};
    float hv[40];
    #pragma unroll
    for (int jj = 0; jj < 40; ++jj) hv[jj] = hT[ci][t0+jj];
    #pragma unroll
    for (int k = 0; k < 8; ++k)
      #pragma unroll
      for (int s = 0; s < 32; ++s)
        acc[s] += hv[s+8-k] * wv[k];
  }
  size_t base = ((size_t)(b*64 + co)*128 + f)*128 + t0;
  float bias = bct[co];
  #pragma unroll
  for (int s = 0; s < 32; ++s)
    out[base + s] = acc[s] + bias + x[base + s];
}

// ----------------------------------------------------------------
extern "C" void kernel_launch(void* const* d_in, const int* in_sizes, int n_in,
                              void* d_out, int out_size, void* d_ws, size_t ws_size,
                              hipStream_t stream){
  const float* x     = (const float*)d_in[0];
  const float* gamma = (const float*)d_in[1];
  const float* beta  = (const float*)d_in[2];
  const float* wih0  = (const float*)d_in[3];   // [2,128,512]
  const float* whh0  = (const float*)d_in[4];   // [2,128,32]
  const float* bih0  = (const float*)d_in[5];
  const float* bhh0  = (const float*)d_in[6];
  const float* wih   = (const float*)d_in[7];   // [3,2,128,64]
  const float* whh   = (const float*)d_in[8];   // [3,2,128,32]
  const float* bih   = (const float*)d_in[9];
  const float* bhh   = (const float*)d_in[10];
  const float* wct   = (const float*)d_in[11];  // [64,64,8]
  const float* bct   = (const float*)d_in[12];
  float* out = (float*)d_out;

  char* wsb = (char*)d_ws;
  float*          scale = (float*)(wsb);                       // 1 KB
  float*          shift = (float*)(wsb + 1024);                // 1 KB
  unsigned short* gx    = (unsigned short*)(wsb + 2048);       // 2*121*512*128*2 = 31,719,424 B
  unsigned short* hA    = (unsigned short*)(wsb + 31721472);   // 7,929,856 B
  unsigned short* hB    = (unsigned short*)(wsb + 39651328);   // 7,929,856 B
  unsigned short* wb0   = (unsigned short*)(wsb + 47581184);   // 262,144 B (16B aligned)
  unsigned short* wlb   = (unsigned short*)(wsb + 47843328);   // 98,304 B  (~47.9 MB total)

  k_norm<<<256, 256, 0, stream>>>(x, gamma, beta, scale, shift);
  k_wcvt<<<512, 256, 0, stream>>>(wih0, wb0, 2*G_*CK_);        // 131072
  k_wcvt<<<192, 256, 0, stream>>>(wih,  wlb, 3*2*G_*64);       // 49152
  k_gx0 <<<512, 256, 0, stream>>>(x, scale, shift, wb0, bih0, bhh0, gx);
  k_lstm<<<1024, 64, 0, stream>>>(gx, whh0, hA);
  unsigned short* hp = hA; unsigned short* hn = hB;
  for (int l = 0; l < 3; ++l){
    k_gxl <<<512, 256, 0, stream>>>(hp, wlb + (size_t)l*2*G_*64,
                                    bih + (size_t)l*2*G_, bhh + (size_t)l*2*G_, gx);
    k_lstm<<<1024, 64, 0, stream>>>(gx, whh + (size_t)l*2*G_*H_, hn);
    unsigned short* tmp = hp; hp = hn; hn = tmp;
  }
  k_conv<<<512, 256, 0, stream>>>(hp, wct, bct, x, out);
}

// Round 4
// 515.787 us; speedup vs baseline: 1.8690x; 1.1189x over previous
//
#include <hip/hip_runtime.h>

#define B_ 4
#define C_ 64
#define F_ 128
#define T_ 128
#define K_ 8
#define H_ 32
#define S_ 121   // T - K + 1
#define N_ 512   // B * F
#define G_ 128   // 4 * H
#define CK_ 512  // C * K

typedef __attribute__((ext_vector_type(8))) short short8;
typedef __attribute__((ext_vector_type(4))) float f32x4;
union FragU { uint4 u; short8 s; };

__device__ __forceinline__ unsigned int pk2(float a, float b){   // RNE f32->bf16 pair
  unsigned int ua = __float_as_uint(a); ua += 0x7fffu + ((ua>>16)&1u);
  unsigned int ub = __float_as_uint(b); ub += 0x7fffu + ((ub>>16)&1u);
  return (ua>>16) | (ub & 0xffff0000u);
}
__device__ __forceinline__ unsigned short bfu(float a){          // RNE f32->bf16
  unsigned int ua = __float_as_uint(a); ua += 0x7fffu + ((ua>>16)&1u);
  return (unsigned short)(ua>>16);
}
__device__ __forceinline__ float ubf(unsigned short v){
  return __uint_as_float(((unsigned int)v) << 16);
}

// ---------------------------------------------------------------- instance norm stats
__global__ __launch_bounds__(256) void k_norm(const float* __restrict__ x,
    const float* __restrict__ gamma, const float* __restrict__ beta,
    float* __restrict__ scale, float* __restrict__ shift){
  int bc = blockIdx.x;
  const float* p = x + (size_t)bc * (F_*T_);
  float s = 0.f, q = 0.f;
  for (int i = threadIdx.x; i < F_*T_; i += 256){ float v = p[i]; s += v; q += v*v; }
  #pragma unroll
  for (int o = 32; o; o >>= 1){ s += __shfl_down(s, o); q += __shfl_down(q, o); }
  __shared__ float ss[4], qq[4];
  int w = threadIdx.x >> 6;
  if ((threadIdx.x & 63) == 0){ ss[w] = s; qq[w] = q; }
  __syncthreads();
  if (threadIdx.x == 0){
    s = ss[0]+ss[1]+ss[2]+ss[3]; q = qq[0]+qq[1]+qq[2]+qq[3];
    float mu  = s / (float)(F_*T_);
    float var = q / (float)(F_*T_) - mu*mu;
    if (var < 0.f) var = 0.f;
    int c = bc & (C_-1);
    float sc = gamma[c] * rsqrtf(var + 1e-5f);
    scale[bc] = sc;
    shift[bc] = beta[c] - mu * sc;
  }
}

// ---------------------------------------------------------------- weight f32 -> bf16
__global__ __launch_bounds__(256) void k_wcvt(const float* __restrict__ a,
    unsigned short* __restrict__ o, int nel){
  int i = blockIdx.x*256 + threadIdx.x;
  if (i < nel) o[i] = bfu(a[i]);
}
// conv weights: bf16 + reverse k within each 8-block (absorbs conv flip into GEMM)
__global__ __launch_bounds__(256) void k_wrev(const float* __restrict__ a,
    unsigned short* __restrict__ o, int nel){
  int i = blockIdx.x*256 + threadIdx.x;
  if (i < nel){ int j = (i & ~7) | (7 - (i & 7)); o[i] = bfu(a[j]); }
}

// ---------------------------------------------------------------- layer-0 projection, MFMA bf16
// gx[d][n][s][g] = sum_{c,k} xn[n][c][s+k] * w0[d][g][ck] + bias   (per-n block)
__global__ __launch_bounds__(256) void k_gx0(const float* __restrict__ x,
    const float* __restrict__ scale, const float* __restrict__ shift,
    const unsigned short* __restrict__ wb0, const float* __restrict__ bi,
    const float* __restrict__ bh, unsigned short* __restrict__ gx){
  __shared__ unsigned int xsp[C_][136];     // packed bf16 pairs (t, t+1); t>=128 zero
  int n = blockIdx.x, b = n >> 7, f = n & 127;
  const float* xb = x + (size_t)b*C_*F_*T_ + (size_t)f*T_;
  for (int i = threadIdx.x; i < C_*136; i += 256){
    int c = i / 136, t = i - c*136;
    float sc = scale[b*C_+c], sh = shift[b*C_+c];
    float v0 = (t   < T_) ? xb[(size_t)c*F_*T_ + t  ]*sc + sh : 0.f;
    float v1 = (t+1 < T_) ? xb[(size_t)c*F_*T_ + t+1]*sc + sh : 0.f;
    xsp[c][t] = pk2(v0, v1);
  }
  __syncthreads();
  int lane = threadIdx.x & 63, wv = threadIdx.x >> 6;
  int ln = lane & 15, quad = lane >> 4;
  int g256[4]; f32x4 acc[8][4];
  #pragma unroll
  for (int gi = 0; gi < 4; ++gi){
    g256[gi] = (wv*4 + gi)*16 + ln;
    float bv = bi[g256[gi]] + bh[g256[gi]];
    #pragma unroll
    for (int st = 0; st < 8; ++st) acc[st][gi] = (f32x4){bv, bv, bv, bv};
  }
  for (int kb = 0; kb < 16; ++kb){
    FragU bfr[4];
    #pragma unroll
    for (int gi = 0; gi < 4; ++gi)
      bfr[gi].u = *(const uint4*)(wb0 + (size_t)g256[gi]*CK_ + kb*32 + quad*8);
    #pragma unroll
    for (int st = 0; st < 8; ++st){
      FragU a;
      const unsigned int* rp = &xsp[kb*4 + quad][st*16 + ln];
      a.u.x = rp[0]; a.u.y = rp[2]; a.u.z = rp[4]; a.u.w = rp[6];
      #pragma unroll
      for (int gi = 0; gi < 4; ++gi)
        acc[st][gi] = __builtin_amdgcn_mfma_f32_16x16x32_bf16(a.s, bfr[gi].s, acc[st][gi], 0, 0, 0);
    }
  }
  #pragma unroll
  for (int st = 0; st < 8; ++st)
    #pragma unroll
    for (int gi = 0; gi < 4; ++gi){
      int d = g256[gi] >> 7, g = g256[gi] & 127;
      #pragma unroll
      for (int r = 0; r < 4; ++r){
        int s = st*16 + quad*4 + r;
        if (s < S_)
          gx[((size_t)(d*N_ + n)*S_ + s)*G_ + g] = bfu(acc[st][gi][r]);
      }
    }
}

// ---------------------------------------------------------------- layers 1..3 projection, MFMA bf16
__global__ __launch_bounds__(256) void k_gxl(const unsigned short* __restrict__ hin,
    const unsigned short* __restrict__ wlb, const float* __restrict__ bi,
    const float* __restrict__ bh, unsigned short* __restrict__ gx){
  __shared__ unsigned int hsp[32][132];     // [i_pair][s], s>=121 zero
  int n = blockIdx.x;
  const unsigned int* hu = (const unsigned int*)hin;
  for (int i = threadIdx.x; i < 32*128; i += 256){
    int s = i >> 5, ip = i & 31;
    hsp[ip][s] = (s < S_) ? hu[((size_t)n*S_ + s)*32 + ip] : 0u;
  }
  __syncthreads();
  int lane = threadIdx.x & 63, wv = threadIdx.x >> 6;
  int ln = lane & 15, quad = lane >> 4;
  int g256[4]; f32x4 acc[8][4];
  #pragma unroll
  for (int gi = 0; gi < 4; ++gi){
    g256[gi] = (wv*4 + gi)*16 + ln;
    float bv = bi[g256[gi]] + bh[g256[gi]];
    #pragma unroll
    for (int st = 0; st < 8; ++st) acc[st][gi] = (f32x4){bv, bv, bv, bv};
  }
  #pragma unroll
  for (int kb = 0; kb < 2; ++kb){
    FragU bfr[4];
    #pragma unroll
    for (int gi = 0; gi < 4; ++gi)
      bfr[gi].u = *(const uint4*)(wlb + (size_t)g256[gi]*64 + kb*32 + quad*8);
    #pragma unroll
    for (int st = 0; st < 8; ++st){
      FragU a;
      int ipb = kb*16 + quad*4, srow = st*16 + ln;
      a.u.x = hsp[ipb+0][srow]; a.u.y = hsp[ipb+1][srow];
      a.u.z = hsp[ipb+2][srow]; a.u.w = hsp[ipb+3][srow];
      #pragma unroll
      for (int gi = 0; gi < 4; ++gi)
        acc[st][gi] = __builtin_amdgcn_mfma_f32_16x16x32_bf16(a.s, bfr[gi].s, acc[st][gi], 0, 0, 0);
    }
  }
  #pragma unroll
  for (int st = 0; st < 8; ++st)
    #pragma unroll
    for (int gi = 0; gi < 4; ++gi){
      int d = g256[gi] >> 7, g = g256[gi] & 127;
      #pragma unroll
      for (int r = 0; r < 4; ++r){
        int s = st*16 + quad*4 + r;
        if (s < S_)
          gx[((size_t)(d*N_ + n)*S_ + s)*G_ + g] = bfu(acc[st][gi][r]);
      }
    }
}

// ---------------------------------------------------------------- LSTM: one wave per (n,dir), no barriers
__global__ __launch_bounds__(64) void k_lstm(const unsigned short* __restrict__ gx,
    const float* __restrict__ whh, unsigned short* __restrict__ hout){
  int blk = blockIdx.x;
  int n = blk & (N_-1), d = blk >> 9;
  int lane = threadIdx.x;
  int j = lane & 31, hi = lane >> 5;
  int r1 = lane;            // rows: lanes 0-31 -> i_j ; lanes 32-63 -> f_j
  int r2 = lane + 64;       //        lanes 0-31 -> g_j ; lanes 32-63 -> o_j
  float w1[32], w2[32];
  const float* wr1 = whh + (size_t)(d*G_ + r1)*H_;
  const float* wr2 = whh + (size_t)(d*G_ + r2)*H_;
  #pragma unroll
  for (int q = 0; q < 8; ++q){
    float4 aa = *(const float4*)(wr1 + q*4);
    float4 bb = *(const float4*)(wr2 + q*4);
    w1[q*4+0]=aa.x; w1[q*4+1]=aa.y; w1[q*4+2]=aa.z; w1[q*4+3]=aa.w;
    w2[q*4+0]=bb.x; w2[q*4+1]=bb.y; w2[q*4+2]=bb.z; w2[q*4+3]=bb.w;
  }
  unsigned short q1[4], q2[4];
  auto gp = [&](int st)->const unsigned short*{
    int s = d ? (S_-1-st) : st;
    return gx + ((size_t)(d*N_ + n)*S_ + s)*G_;
  };
  #pragma unroll
  for (int u = 0; u < 4; ++u){ const unsigned short* p = gp(u); q1[u] = p[r1]; q2[u] = p[r2]; }
  float hv = 0.f, c = 0.f;
  for (int stb = 0; stb < 31; ++stb){
    #pragma unroll
    for (int u = 0; u < 4; ++u){
      int st = stb*4 + u;
      if (st >= S_) break;                       // wave-uniform
      float acc1 = ubf(q1[u]), acc2 = ubf(q2[u]);
      int pf = st + 4; if (pf > S_-1) pf = S_-1; // clamped overfetch, value unused
      const unsigned short* pp = gp(pf);
      q1[u] = pp[r1]; q2[u] = pp[r2];
      float s1 = acc1, s2 = 0.f, s3 = acc2, s4 = 0.f;
      #pragma unroll
      for (int k = 0; k < 32; k += 2){
        float ha = __uint_as_float(__builtin_amdgcn_readlane(__float_as_uint(hv), k));
        float hb = __uint_as_float(__builtin_amdgcn_readlane(__float_as_uint(hv), k+1));
        s1 += ha*w1[k]; s2 += hb*w1[k+1];
        s3 += ha*w2[k]; s4 += hb*w2[k+1];
      }
      acc1 = s1 + s2; acc2 = s3 + s4;
      float a1 = 1.f/(1.f + __expf(-acc1));            // sigmoid (i or f)
      float x2 = hi ? acc2 : 2.f*acc2;                 // shared-exp: o sigm / g tanh
      float tt = 1.f/(1.f + __expf(-x2));
      float a2 = hi ? tt : 2.f*tt - 1.f;
      float b1 = __shfl_xor(a1, 32);
      float b2 = __shfl_xor(a2, 32);
      float i_ = hi ? b1 : a1;
      float f_ = hi ? a1 : b1;
      float g_ = hi ? b2 : a2;
      float o_ = hi ? a2 : b2;
      c = f_*c + i_*g_;
      float tc = 1.f/(1.f + __expf(-2.f*c));
      hv = o_*(2.f*tc - 1.f);
      if (!hi){
        int s = d ? (S_-1-st) : st;
        hout[((size_t)n*S_ + s)*64 + d*32 + j] = bfu(hv);
      }
    }
  }
}

// ---------------------------------------------------------------- ConvTranspose via MFMA + bias + residual
// y[co,t] = sum_{ci,k} h[ci][t-k] * wct[co][ci][k]   == GEMM: A=wA[co][(ci,j)], B=h[(ci,j)][t]
// wA pre-relaid with k reversed: element j pairs with h[ci][t-7+j].
__global__ __launch_bounds__(256) void k_conv(const unsigned short* __restrict__ hin,
    const unsigned short* __restrict__ wA, const float* __restrict__ bct,
    const float* __restrict__ x, float* __restrict__ out){
  __shared__ unsigned int hraw[S_][33];     // [s][ip] dwords, stride 33 (swizzle for transpose read)
  __shared__ unsigned int hp2[64][144];     // overlapping bf16 pairs [ci][col], col=t'+8, stride 144
  int n = blockIdx.x, b = n >> 7, f = n & 127;
  const unsigned int* hu = (const unsigned int*)hin + (size_t)n*S_*32;
  for (int i = threadIdx.x; i < S_*32; i += 256)
    hraw[i >> 5][i & 31] = hu[i];
  __syncthreads();
  const unsigned short* hr16 = (const unsigned short*)&hraw[0][0];  // u16 idx = s*66 + ci
  for (int it = threadIdx.x; it < 64*136; it += 256){
    int ci = it / 136, col = it - ci*136;
    int t0 = col - 8;
    unsigned int lo = (t0 >= 0 && t0 < S_)     ? hr16[t0*66 + ci]     : 0u;
    unsigned int hi2 = (t0+1 >= 0 && t0+1 < S_) ? hr16[(t0+1)*66 + ci] : 0u;
    hp2[ci][col] = lo | (hi2 << 16);
  }
  __syncthreads();
  int lane = threadIdx.x & 63, wv = threadIdx.x >> 6;
  int ln = lane & 15, quad = lane >> 4;
  const unsigned short* wp = wA + (size_t)(wv*16 + ln)*512;
  f32x4 acc[8];
  #pragma unroll
  for (int nt = 0; nt < 8; ++nt) acc[nt] = (f32x4){0.f,0.f,0.f,0.f};
  for (int kb = 0; kb < 16; ++kb){
    FragU afr; afr.u = *(const uint4*)(wp + kb*32 + quad*8);
    int ci = kb*4 + quad;
    #pragma unroll
    for (int nt = 0; nt < 8; ++nt){
      FragU bfr;
      const unsigned int* rp = &hp2[ci][nt*16 + ln + 1];
      bfr.u.x = rp[0]; bfr.u.y = rp[2]; bfr.u.z = rp[4]; bfr.u.w = rp[6];
      acc[nt] = __builtin_amdgcn_mfma_f32_16x16x32_bf16(afr.s, bfr.s, acc[nt], 0, 0, 0);
    }
  }
  float bb[4];
  #pragma unroll
  for (int r = 0; r < 4; ++r) bb[r] = bct[wv*16 + quad*4 + r];
  #pragma unroll
  for (int nt = 0; nt < 8; ++nt)
    #pragma unroll
    for (int r = 0; r < 4; ++r){
      int co = wv*16 + quad*4 + r, t = nt*16 + ln;
      size_t idx = ((size_t)(b*64 + co)*128 + f)*128 + t;
      out[idx] = acc[nt][r] + bb[r] + x[idx];
    }
}

// ----------------------------------------------------------------
extern "C" void kernel_launch(void* const* d_in, const int* in_sizes, int n_in,
                              void* d_out, int out_size, void* d_ws, size_t ws_size,
                              hipStream_t stream){
  const float* x     = (const float*)d_in[0];
  const float* gamma = (const float*)d_in[1];
  const float* beta  = (const float*)d_in[2];
  const float* wih0  = (const float*)d_in[3];   // [2,128,512]
  const float* whh0  = (const float*)d_in[4];   // [2,128,32]
  const float* bih0  = (const float*)d_in[5];
  const float* bhh0  = (const float*)d_in[6];
  const float* wih   = (const float*)d_in[7];   // [3,2,128,64]
  const float* whh   = (const float*)d_in[8];   // [3,2,128,32]
  const float* bih   = (const float*)d_in[9];
  const float* bhh   = (const float*)d_in[10];
  const float* wct   = (const float*)d_in[11];  // [64,64,8]
  const float* bct   = (const float*)d_in[12];
  float* out = (float*)d_out;

  char* wsb = (char*)d_ws;
  float*          scale = (float*)(wsb);                       // 1 KB
  float*          shift = (float*)(wsb + 1024);                // 1 KB
  unsigned short* gx    = (unsigned short*)(wsb + 2048);       // 31,719,424 B
  unsigned short* hA    = (unsigned short*)(wsb + 31721472);   // 7,929,856 B
  unsigned short* hB    = (unsigned short*)(wsb + 39651328);   // 7,929,856 B
  unsigned short* wb0   = (unsigned short*)(wsb + 47581184);   // 262,144 B
  unsigned short* wlb   = (unsigned short*)(wsb + 47843328);   // 98,304 B
  unsigned short* wcv   = (unsigned short*)(wsb + 47941632);   // 65,536 B  (~48.0 MB total)

  k_norm<<<256, 256, 0, stream>>>(x, gamma, beta, scale, shift);
  k_wcvt<<<512, 256, 0, stream>>>(wih0, wb0, 2*G_*CK_);
  k_wcvt<<<192, 256, 0, stream>>>(wih,  wlb, 3*2*G_*64);
  k_wrev<<<128, 256, 0, stream>>>(wct,  wcv, 64*512);
  k_gx0 <<<512, 256, 0, stream>>>(x, scale, shift, wb0, bih0, bhh0, gx);
  k_lstm<<<1024, 64, 0, stream>>>(gx, whh0, hA);
  unsigned short* hp = hA; unsigned short* hn = hB;
  for (int l = 0; l < 3; ++l){
    k_gxl <<<512, 256, 0, stream>>>(hp, wlb + (size_t)l*2*G_*64,
                                    bih + (size_t)l*2*G_, bhh + (size_t)l*2*G_, gx);
    k_lstm<<<1024, 64, 0, stream>>>(gx, whh + (size_t)l*2*G_*H_, hn);
    unsigned short* tmp = hp; hp = hn; hn = tmp;
  }
  k_conv<<<512, 256, 0, stream>>>(hp, wcv, bct, x, out);
}

// Round 5
// 472.851 us; speedup vs baseline: 2.0387x; 1.0908x over previous
//
#include <hip/hip_runtime.h>

#define B_ 4
#define C_ 64
#define F_ 128
#define T_ 128
#define K_ 8
#define H_ 32
#define S_ 121   // T - K + 1
#define N_ 512   // B * F
#define G_ 128   // 4 * H
#define CK_ 512  // C * K

typedef __attribute__((ext_vector_type(8))) short short8;
typedef __attribute__((ext_vector_type(4))) float f32x4;
union FragU { uint4 u; short8 s; };

__device__ __forceinline__ unsigned int pk2(float a, float b){   // RNE f32->bf16 pair
  unsigned int ua = __float_as_uint(a); ua += 0x7fffu + ((ua>>16)&1u);
  unsigned int ub = __float_as_uint(b); ub += 0x7fffu + ((ub>>16)&1u);
  return (ua>>16) | (ub & 0xffff0000u);
}
__device__ __forceinline__ unsigned short bfu(float a){          // RNE f32->bf16
  unsigned int ua = __float_as_uint(a); ua += 0x7fffu + ((ua>>16)&1u);
  return (unsigned short)(ua>>16);
}
__device__ __forceinline__ float ubf(unsigned short v){
  return __uint_as_float(((unsigned int)v) << 16);
}

// gx gate-pair interleaved slot: lane l of k_lstm reads one dword = (row l | row l+64 <<16)
__device__ __forceinline__ int gslot(int g){ return ((g & 63) << 1) | (g >> 6); }

// ---------------------------------------------------------------- instance norm stats
__global__ __launch_bounds__(256) void k_norm(const float* __restrict__ x,
    const float* __restrict__ gamma, const float* __restrict__ beta,
    float* __restrict__ scale, float* __restrict__ shift){
  int bc = blockIdx.x;
  const float* p = x + (size_t)bc * (F_*T_);
  float s = 0.f, q = 0.f;
  for (int i = threadIdx.x; i < F_*T_; i += 256){ float v = p[i]; s += v; q += v*v; }
  #pragma unroll
  for (int o = 32; o; o >>= 1){ s += __shfl_down(s, o); q += __shfl_down(q, o); }
  __shared__ float ss[4], qq[4];
  int w = threadIdx.x >> 6;
  if ((threadIdx.x & 63) == 0){ ss[w] = s; qq[w] = q; }
  __syncthreads();
  if (threadIdx.x == 0){
    s = ss[0]+ss[1]+ss[2]+ss[3]; q = qq[0]+qq[1]+qq[2]+qq[3];
    float mu  = s / (float)(F_*T_);
    float var = q / (float)(F_*T_) - mu*mu;
    if (var < 0.f) var = 0.f;
    int c = bc & (C_-1);
    float sc = gamma[c] * rsqrtf(var + 1e-5f);
    scale[bc] = sc;
    shift[bc] = beta[c] - mu * sc;
  }
}

// ---------------------------------------------------------------- weight f32 -> bf16
__global__ __launch_bounds__(256) void k_wcvt(const float* __restrict__ a,
    unsigned short* __restrict__ o, int nel){
  int i = blockIdx.x*256 + threadIdx.x;
  if (i < nel) o[i] = bfu(a[i]);
}
// conv weights: bf16 + reverse k within each 8-block (absorbs conv flip into GEMM)
__global__ __launch_bounds__(256) void k_wrev(const float* __restrict__ a,
    unsigned short* __restrict__ o, int nel){
  int i = blockIdx.x*256 + threadIdx.x;
  if (i < nel){ int j = (i & ~7) | (7 - (i & 7)); o[i] = bfu(a[j]); }
}

// ---------------------------------------------------------------- layer-0 projection, MFMA bf16
__global__ __launch_bounds__(256) void k_gx0(const float* __restrict__ x,
    const float* __restrict__ scale, const float* __restrict__ shift,
    const unsigned short* __restrict__ wb0, const float* __restrict__ bi,
    const float* __restrict__ bh, unsigned short* __restrict__ gx){
  __shared__ unsigned int xsp[C_][136];     // packed bf16 pairs (t, t+1); t>=128 zero
  int n = blockIdx.x, b = n >> 7, f = n & 127;
  const float* xb = x + (size_t)b*C_*F_*T_ + (size_t)f*T_;
  for (int i = threadIdx.x; i < C_*136; i += 256){
    int c = i / 136, t = i - c*136;
    float sc = scale[b*C_+c], sh = shift[b*C_+c];
    float v0 = (t   < T_) ? xb[(size_t)c*F_*T_ + t  ]*sc + sh : 0.f;
    float v1 = (t+1 < T_) ? xb[(size_t)c*F_*T_ + t+1]*sc + sh : 0.f;
    xsp[c][t] = pk2(v0, v1);
  }
  __syncthreads();
  int lane = threadIdx.x & 63, wv = threadIdx.x >> 6;
  int ln = lane & 15, quad = lane >> 4;
  int g256[4]; f32x4 acc[8][4];
  #pragma unroll
  for (int gi = 0; gi < 4; ++gi){
    g256[gi] = (wv*4 + gi)*16 + ln;
    float bv = bi[g256[gi]] + bh[g256[gi]];
    #pragma unroll
    for (int st = 0; st < 8; ++st) acc[st][gi] = (f32x4){bv, bv, bv, bv};
  }
  for (int kb = 0; kb < 16; ++kb){
    FragU bfr[4];
    #pragma unroll
    for (int gi = 0; gi < 4; ++gi)
      bfr[gi].u = *(const uint4*)(wb0 + (size_t)g256[gi]*CK_ + kb*32 + quad*8);
    #pragma unroll
    for (int st = 0; st < 8; ++st){
      FragU a;
      const unsigned int* rp = &xsp[kb*4 + quad][st*16 + ln];
      a.u.x = rp[0]; a.u.y = rp[2]; a.u.z = rp[4]; a.u.w = rp[6];
      #pragma unroll
      for (int gi = 0; gi < 4; ++gi)
        acc[st][gi] = __builtin_amdgcn_mfma_f32_16x16x32_bf16(a.s, bfr[gi].s, acc[st][gi], 0, 0, 0);
    }
  }
  #pragma unroll
  for (int st = 0; st < 8; ++st)
    #pragma unroll
    for (int gi = 0; gi < 4; ++gi){
      int d = g256[gi] >> 7, g = g256[gi] & 127;
      #pragma unroll
      for (int r = 0; r < 4; ++r){
        int s = st*16 + quad*4 + r;
        if (s < S_)
          gx[((size_t)(d*N_ + n)*S_ + s)*G_ + gslot(g)] = bfu(acc[st][gi][r]);
      }
    }
}

// ---------------------------------------------------------------- layers 1..3 projection, MFMA bf16
__global__ __launch_bounds__(256) void k_gxl(const unsigned short* __restrict__ hin,
    const unsigned short* __restrict__ wlb, const float* __restrict__ bi,
    const float* __restrict__ bh, unsigned short* __restrict__ gx){
  __shared__ unsigned int hsp[32][132];     // [i_pair][s], s>=121 zero
  int n = blockIdx.x;
  const unsigned int* hu = (const unsigned int*)hin;
  for (int i = threadIdx.x; i < 32*128; i += 256){
    int s = i >> 5, ip = i & 31;
    hsp[ip][s] = (s < S_) ? hu[((size_t)n*S_ + s)*32 + ip] : 0u;
  }
  __syncthreads();
  int lane = threadIdx.x & 63, wv = threadIdx.x >> 6;
  int ln = lane & 15, quad = lane >> 4;
  int g256[4]; f32x4 acc[8][4];
  #pragma unroll
  for (int gi = 0; gi < 4; ++gi){
    g256[gi] = (wv*4 + gi)*16 + ln;
    float bv = bi[g256[gi]] + bh[g256[gi]];
    #pragma unroll
    for (int st = 0; st < 8; ++st) acc[st][gi] = (f32x4){bv, bv, bv, bv};
  }
  #pragma unroll
  for (int kb = 0; kb < 2; ++kb){
    FragU bfr[4];
    #pragma unroll
    for (int gi = 0; gi < 4; ++gi)
      bfr[gi].u = *(const uint4*)(wlb + (size_t)g256[gi]*64 + kb*32 + quad*8);
    #pragma unroll
    for (int st = 0; st < 8; ++st){
      FragU a;
      int ipb = kb*16 + quad*4, srow = st*16 + ln;
      a.u.x = hsp[ipb+0][srow]; a.u.y = hsp[ipb+1][srow];
      a.u.z = hsp[ipb+2][srow]; a.u.w = hsp[ipb+3][srow];
      #pragma unroll
      for (int gi = 0; gi < 4; ++gi)
        acc[st][gi] = __builtin_amdgcn_mfma_f32_16x16x32_bf16(a.s, bfr[gi].s, acc[st][gi], 0, 0, 0);
    }
  }
  #pragma unroll
  for (int st = 0; st < 8; ++st)
    #pragma unroll
    for (int gi = 0; gi < 4; ++gi){
      int d = g256[gi] >> 7, g = g256[gi] & 127;
      #pragma unroll
      for (int r = 0; r < 4; ++r){
        int s = st*16 + quad*4 + r;
        if (s < S_)
          gx[((size_t)(d*N_ + n)*S_ + s)*G_ + gslot(g)] = bfu(acc[st][gi][r]);
      }
    }
}

// ---------------------------------------------------------------- LSTM: one wave per (n,dir)
// branch-free, 8-deep dword prefetch ring; lane l reads one dword = (row l | row l+64<<16)
__global__ __launch_bounds__(64) void k_lstm(const unsigned short* __restrict__ gx,
    const float* __restrict__ whh, unsigned short* __restrict__ hout){
  int blk = blockIdx.x;
  int n = blk & (N_-1), d = blk >> 9;
  int lane = threadIdx.x;
  int j = lane & 31, hi = lane >> 5;
  float w1[32], w2[32];
  const float* wr1 = whh + (size_t)(d*G_ + lane)*H_;
  const float* wr2 = whh + (size_t)(d*G_ + lane + 64)*H_;
  #pragma unroll
  for (int q = 0; q < 8; ++q){
    float4 aa = *(const float4*)(wr1 + q*4);
    float4 bb = *(const float4*)(wr2 + q*4);
    w1[q*4+0]=aa.x; w1[q*4+1]=aa.y; w1[q*4+2]=aa.z; w1[q*4+3]=aa.w;
    w2[q*4+0]=bb.x; w2[q*4+1]=bb.y; w2[q*4+2]=bb.z; w2[q*4+3]=bb.w;
  }
  const unsigned int* gxu = (const unsigned int*)gx;
  ptrdiff_t stride = d ? -64 : 64;
  const unsigned int* p0 = gxu + ((size_t)(d*N_ + n)*S_ + (d ? (S_-1) : 0))*64 + lane;
  unsigned int buf[8];
  #pragma unroll
  for (int u = 0; u < 8; ++u) buf[u] = p0[stride*u];
  const unsigned int* pf = p0 + stride*8;   // overfetch past chain end stays inside gx buffer

  ptrdiff_t hstride = d ? -64 : 64;
  unsigned short* hop = hout + (size_t)n*S_*64 + (d ? (size_t)(S_-1)*64 : 0) + d*32 + j;

  float hv = 0.f, c = 0.f;
  auto step = [&](unsigned int cur){
    float acc1 = __uint_as_float(cur << 16);          // row lane     (i / f)
    float acc2 = __uint_as_float(cur & 0xffff0000u);  // row lane+64  (g / o)
    float s1 = acc1, s2 = 0.f, s3 = acc2, s4 = 0.f;
    #pragma unroll
    for (int k = 0; k < 32; k += 2){
      float ha = __uint_as_float(__builtin_amdgcn_readlane(__float_as_uint(hv), k));
      float hb = __uint_as_float(__builtin_amdgcn_readlane(__float_as_uint(hv), k+1));
      s1 += ha*w1[k]; s2 += hb*w1[k+1];
      s3 += ha*w2[k]; s4 += hb*w2[k+1];
    }
    acc1 = s1 + s2; acc2 = s3 + s4;
    float a1 = 1.f/(1.f + __expf(-acc1));            // sigmoid (i or f)
    float x2 = hi ? acc2 : 2.f*acc2;                 // shared-exp: o sigm / g tanh
    float tt = 1.f/(1.f + __expf(-x2));
    float a2 = hi ? tt : 2.f*tt - 1.f;
    float b1 = __shfl_xor(a1, 32);
    float b2 = __shfl_xor(a2, 32);
    float i_ = hi ? b1 : a1;
    float f_ = hi ? a1 : b1;
    float g_ = hi ? b2 : a2;
    float o_ = hi ? a2 : b2;
    c = f_*c + i_*g_;
    float tc = 1.f/(1.f + __expf(-2.f*c));
    hv = o_*(2.f*tc - 1.f);
    if (!hi) *hop = bfu(hv);
    hop += hstride;
  };

  for (int ob = 0; ob < 15; ++ob){        // steps 0..119
    #pragma unroll
    for (int u = 0; u < 8; ++u){
      unsigned int cur = buf[u];
      buf[u] = *pf; pf += stride;          // prefetch st+8 (overfetch harmless, never consumed)
      step(cur);
    }
  }
  step(buf[0]);                            // step 120 (loaded at st=112)
}

// ---------------------------------------------------------------- ConvTranspose via MFMA + bias + residual
__global__ __launch_bounds__(256) void k_conv(const unsigned short* __restrict__ hin,
    const unsigned short* __restrict__ wA, const float* __restrict__ bct,
    const float* __restrict__ x, float* __restrict__ out){
  __shared__ unsigned int hraw[S_][33];     // [s][ip] dwords, stride 33 (swizzle for transpose read)
  __shared__ unsigned int hp2[64][144];     // overlapping bf16 pairs [ci][col], col=t'+8, stride 144
  int n = blockIdx.x, b = n >> 7, f = n & 127;
  const unsigned int* hu = (const unsigned int*)hin + (size_t)n*S_*32;
  for (int i = threadIdx.x; i < S_*32; i += 256)
    hraw[i >> 5][i & 31] = hu[i];
  __syncthreads();
  const unsigned short* hr16 = (const unsigned short*)&hraw[0][0];  // u16 idx = s*66 + ci
  for (int it = threadIdx.x; it < 64*136; it += 256){
    int ci = it / 136, col = it - ci*136;
    int t0 = col - 8;
    unsigned int lo  = (t0 >= 0 && t0 < S_)     ? hr16[t0*66 + ci]     : 0u;
    unsigned int hi2 = (t0+1 >= 0 && t0+1 < S_) ? hr16[(t0+1)*66 + ci] : 0u;
    hp2[ci][col] = lo | (hi2 << 16);
  }
  __syncthreads();
  int lane = threadIdx.x & 63, wv = threadIdx.x >> 6;
  int ln = lane & 15, quad = lane >> 4;
  const unsigned short* wp = wA + (size_t)(wv*16 + ln)*512;
  f32x4 acc[8];
  #pragma unroll
  for (int nt = 0; nt < 8; ++nt) acc[nt] = (f32x4){0.f,0.f,0.f,0.f};
  for (int kb = 0; kb < 16; ++kb){
    FragU afr; afr.u = *(const uint4*)(wp + kb*32 + quad*8);
    int ci = kb*4 + quad;
    #pragma unroll
    for (int nt = 0; nt < 8; ++nt){
      FragU bfr;
      const unsigned int* rp = &hp2[ci][nt*16 + ln + 1];
      bfr.u.x = rp[0]; bfr.u.y = rp[2]; bfr.u.z = rp[4]; bfr.u.w = rp[6];
      acc[nt] = __builtin_amdgcn_mfma_f32_16x16x32_bf16(afr.s, bfr.s, acc[nt], 0, 0, 0);
    }
  }
  float bb[4];
  #pragma unroll
  for (int r = 0; r < 4; ++r) bb[r] = bct[wv*16 + quad*4 + r];
  #pragma unroll
  for (int nt = 0; nt < 8; ++nt)
    #pragma unroll
    for (int r = 0; r < 4; ++r){
      int co = wv*16 + quad*4 + r, t = nt*16 + ln;
      size_t idx = ((size_t)(b*64 + co)*128 + f)*128 + t;
      out[idx] = acc[nt][r] + bb[r] + x[idx];
    }
}

// ----------------------------------------------------------------
extern "C" void kernel_launch(void* const* d_in, const int* in_sizes, int n_in,
                              void* d_out, int out_size, void* d_ws, size_t ws_size,
                              hipStream_t stream){
  const float* x     = (const float*)d_in[0];
  const float* gamma = (const float*)d_in[1];
  const float* beta  = (const float*)d_in[2];
  const float* wih0  = (const float*)d_in[3];   // [2,128,512]
  const float* whh0  = (const float*)d_in[4];   // [2,128,32]
  const float* bih0  = (const float*)d_in[5];
  const float* bhh0  = (const float*)d_in[6];
  const float* wih   = (const float*)d_in[7];   // [3,2,128,64]
  const float* whh   = (const float*)d_in[8];   // [3,2,128,32]
  const float* bih   = (const float*)d_in[9];
  const float* bhh   = (const float*)d_in[10];
  const float* wct   = (const float*)d_in[11];  // [64,64,8]
  const float* bct   = (const float*)d_in[12];
  float* out = (float*)d_out;

  char* wsb = (char*)d_ws;
  float*          scale = (float*)(wsb);                       // 1 KB
  float*          shift = (float*)(wsb + 1024);                // 1 KB
  unsigned short* gx    = (unsigned short*)(wsb + 2048);       // 31,719,424 B
  unsigned short* hA    = (unsigned short*)(wsb + 31721472);   // 7,929,856 B
  unsigned short* hB    = (unsigned short*)(wsb + 39651328);   // 7,929,856 B
  unsigned short* wb0   = (unsigned short*)(wsb + 47581184);   // 262,144 B
  unsigned short* wlb   = (unsigned short*)(wsb + 47843328);   // 98,304 B
  unsigned short* wcv   = (unsigned short*)(wsb + 47941632);   // 65,536 B  (~48.0 MB total)

  k_norm<<<256, 256, 0, stream>>>(x, gamma, beta, scale, shift);
  k_wcvt<<<512, 256, 0, stream>>>(wih0, wb0, 2*G_*CK_);
  k_wcvt<<<192, 256, 0, stream>>>(wih,  wlb, 3*2*G_*64);
  k_wrev<<<128, 256, 0, stream>>>(wct,  wcv, 64*512);
  k_gx0 <<<512, 256, 0, stream>>>(x, scale, shift, wb0, bih0, bhh0, gx);
  k_lstm<<<1024, 64, 0, stream>>>(gx, whh0, hA);
  unsigned short* hp = hA; unsigned short* hn = hB;
  for (int l = 0; l < 3; ++l){
    k_gxl <<<512, 256, 0, stream>>>(hp, wlb + (size_t)l*2*G_*64,
                                    bih + (size_t)l*2*G_, bhh + (size_t)l*2*G_, gx);
    k_lstm<<<1024, 64, 0, stream>>>(gx, whh + (size_t)l*2*G_*H_, hn);
    unsigned short* tmp = hp; hp = hn; hn = tmp;
  }
  k_conv<<<512, 256, 0, stream>>>(hp, wcv, bct, x, out);
}

// Round 6
// 472.440 us; speedup vs baseline: 2.0405x; 1.0009x over previous
//
#include <hip/hip_runtime.h>

#define B_ 4
#define C_ 64
#define F_ 128
#define T_ 128
#define K_ 8
#define H_ 32
#define S_ 121   // T - K + 1
#define N_ 512   // B * F
#define G_ 128   // 4 * H
#define CK_ 512  // C * K

typedef __attribute__((ext_vector_type(8))) short short8;
typedef __attribute__((ext_vector_type(4))) float f32x4;
union FragU { uint4 u; short8 s; };

__device__ __forceinline__ unsigned int pk2(float a, float b){   // RNE f32->bf16 pair
  unsigned int ua = __float_as_uint(a); ua += 0x7fffu + ((ua>>16)&1u);
  unsigned int ub = __float_as_uint(b); ub += 0x7fffu + ((ub>>16)&1u);
  return (ua>>16) | (ub & 0xffff0000u);
}
__device__ __forceinline__ unsigned short bfu(float a){          // RNE f32->bf16
  unsigned int ua = __float_as_uint(a); ua += 0x7fffu + ((ua>>16)&1u);
  return (unsigned short)(ua>>16);
}
__device__ __forceinline__ float ubf(unsigned short v){
  return __uint_as_float(((unsigned int)v) << 16);
}

// gx gate-pair interleaved slot: lane l of k_lstm reads one dword = (row l | row l+64 <<16)
__device__ __forceinline__ int gslot(int g){ return ((g & 63) << 1) | (g >> 6); }

// ---------------------------------------------------------------- instance norm stats
__global__ __launch_bounds__(256) void k_norm(const float* __restrict__ x,
    const float* __restrict__ gamma, const float* __restrict__ beta,
    float* __restrict__ scale, float* __restrict__ shift){
  int bc = blockIdx.x;
  const float* p = x + (size_t)bc * (F_*T_);
  float s = 0.f, q = 0.f;
  for (int i = threadIdx.x; i < F_*T_; i += 256){ float v = p[i]; s += v; q += v*v; }
  #pragma unroll
  for (int o = 32; o; o >>= 1){ s += __shfl_down(s, o); q += __shfl_down(q, o); }
  __shared__ float ss[4], qq[4];
  int w = threadIdx.x >> 6;
  if ((threadIdx.x & 63) == 0){ ss[w] = s; qq[w] = q; }
  __syncthreads();
  if (threadIdx.x == 0){
    s = ss[0]+ss[1]+ss[2]+ss[3]; q = qq[0]+qq[1]+qq[2]+qq[3];
    float mu  = s / (float)(F_*T_);
    float var = q / (float)(F_*T_) - mu*mu;
    if (var < 0.f) var = 0.f;
    int c = bc & (C_-1);
    float sc = gamma[c] * rsqrtf(var + 1e-5f);
    scale[bc] = sc;
    shift[bc] = beta[c] - mu * sc;
  }
}

// ---------------------------------------------------------------- weight f32 -> bf16
__global__ __launch_bounds__(256) void k_wcvt(const float* __restrict__ a,
    unsigned short* __restrict__ o, int nel){
  int i = blockIdx.x*256 + threadIdx.x;
  if (i < nel) o[i] = bfu(a[i]);
}
// conv weights: bf16 + reverse k within each 8-block (absorbs conv flip into GEMM)
__global__ __launch_bounds__(256) void k_wrev(const float* __restrict__ a,
    unsigned short* __restrict__ o, int nel){
  int i = blockIdx.x*256 + threadIdx.x;
  if (i < nel){ int j = (i & ~7) | (7 - (i & 7)); o[i] = bfu(a[j]); }
}

// ---------------------------------------------------------------- layer-0 projection, MFMA bf16
__global__ __launch_bounds__(256) void k_gx0(const float* __restrict__ x,
    const float* __restrict__ scale, const float* __restrict__ shift,
    const unsigned short* __restrict__ wb0, const float* __restrict__ bi,
    const float* __restrict__ bh, unsigned short* __restrict__ gx){
  __shared__ unsigned int xsp[C_][136];     // packed bf16 pairs (t, t+1); t>=128 zero
  int n = blockIdx.x, b = n >> 7, f = n & 127;
  const float* xb = x + (size_t)b*C_*F_*T_ + (size_t)f*T_;
  for (int i = threadIdx.x; i < C_*136; i += 256){
    int c = i / 136, t = i - c*136;
    float sc = scale[b*C_+c], sh = shift[b*C_+c];
    float v0 = (t   < T_) ? xb[(size_t)c*F_*T_ + t  ]*sc + sh : 0.f;
    float v1 = (t+1 < T_) ? xb[(size_t)c*F_*T_ + t+1]*sc + sh : 0.f;
    xsp[c][t] = pk2(v0, v1);
  }
  __syncthreads();
  int lane = threadIdx.x & 63, wv = threadIdx.x >> 6;
  int ln = lane & 15, quad = lane >> 4;
  int g256[4]; f32x4 acc[8][4];
  #pragma unroll
  for (int gi = 0; gi < 4; ++gi){
    g256[gi] = (wv*4 + gi)*16 + ln;
    float bv = bi[g256[gi]] + bh[g256[gi]];
    #pragma unroll
    for (int st = 0; st < 8; ++st) acc[st][gi] = (f32x4){bv, bv, bv, bv};
  }
  for (int kb = 0; kb < 16; ++kb){
    FragU bfr[4];
    #pragma unroll
    for (int gi = 0; gi < 4; ++gi)
      bfr[gi].u = *(const uint4*)(wb0 + (size_t)g256[gi]*CK_ + kb*32 + quad*8);
    #pragma unroll
    for (int st = 0; st < 8; ++st){
      FragU a;
      const unsigned int* rp = &xsp[kb*4 + quad][st*16 + ln];
      a.u.x = rp[0]; a.u.y = rp[2]; a.u.z = rp[4]; a.u.w = rp[6];
      #pragma unroll
      for (int gi = 0; gi < 4; ++gi)
        acc[st][gi] = __builtin_amdgcn_mfma_f32_16x16x32_bf16(a.s, bfr[gi].s, acc[st][gi], 0, 0, 0);
    }
  }
  #pragma unroll
  for (int st = 0; st < 8; ++st)
    #pragma unroll
    for (int gi = 0; gi < 4; ++gi){
      int d = g256[gi] >> 7, g = g256[gi] & 127;
      #pragma unroll
      for (int r = 0; r < 4; ++r){
        int s = st*16 + quad*4 + r;
        if (s < S_)
          gx[((size_t)(d*N_ + n)*S_ + s)*G_ + gslot(g)] = bfu(acc[st][gi][r]);
      }
    }
}

// ---------------------------------------------------------------- layers 1..3 projection, MFMA bf16
__global__ __launch_bounds__(256) void k_gxl(const unsigned short* __restrict__ hin,
    const unsigned short* __restrict__ wlb, const float* __restrict__ bi,
    const float* __restrict__ bh, unsigned short* __restrict__ gx){
  __shared__ unsigned int hsp[32][132];     // [i_pair][s], s>=121 zero
  int n = blockIdx.x;
  const unsigned int* hu = (const unsigned int*)hin;
  for (int i = threadIdx.x; i < 32*128; i += 256){
    int s = i >> 5, ip = i & 31;
    hsp[ip][s] = (s < S_) ? hu[((size_t)n*S_ + s)*32 + ip] : 0u;
  }
  __syncthreads();
  int lane = threadIdx.x & 63, wv = threadIdx.x >> 6;
  int ln = lane & 15, quad = lane >> 4;
  int g256[4]; f32x4 acc[8][4];
  #pragma unroll
  for (int gi = 0; gi < 4; ++gi){
    g256[gi] = (wv*4 + gi)*16 + ln;
    float bv = bi[g256[gi]] + bh[g256[gi]];
    #pragma unroll
    for (int st = 0; st < 8; ++st) acc[st][gi] = (f32x4){bv, bv, bv, bv};
  }
  #pragma unroll
  for (int kb = 0; kb < 2; ++kb){
    FragU bfr[4];
    #pragma unroll
    for (int gi = 0; gi < 4; ++gi)
      bfr[gi].u = *(const uint4*)(wlb + (size_t)g256[gi]*64 + kb*32 + quad*8);
    #pragma unroll
    for (int st = 0; st < 8; ++st){
      FragU a;
      int ipb = kb*16 + quad*4, srow = st*16 + ln;
      a.u.x = hsp[ipb+0][srow]; a.u.y = hsp[ipb+1][srow];
      a.u.z = hsp[ipb+2][srow]; a.u.w = hsp[ipb+3][srow];
      #pragma unroll
      for (int gi = 0; gi < 4; ++gi)
        acc[st][gi] = __builtin_amdgcn_mfma_f32_16x16x32_bf16(a.s, bfr[gi].s, acc[st][gi], 0, 0, 0);
    }
  }
  #pragma unroll
  for (int st = 0; st < 8; ++st)
    #pragma unroll
    for (int gi = 0; gi < 4; ++gi){
      int d = g256[gi] >> 7, g = g256[gi] & 127;
      #pragma unroll
      for (int r = 0; r < 4; ++r){
        int s = st*16 + quad*4 + r;
        if (s < S_)
          gx[((size_t)(d*N_ + n)*S_ + s)*G_ + gslot(g)] = bfu(acc[st][gi][r]);
      }
    }
}

// ---------------------------------------------------------------- LSTM: one wave per (n,dir)
// branch-free, 8-deep dword prefetch ring; lane l reads one dword = (row l | row l+64<<16)
// __launch_bounds__(64, 1): 1 wave/EU floor -> full VGPR budget so w1/w2 stay resident
// (at 1024 waves / 256 CUs occupancy is TLP-capped anyway; round-5 fix for VGPR_Count=52)
__global__ __launch_bounds__(64, 1) void k_lstm(const unsigned short* __restrict__ gx,
    const float* __restrict__ whh, unsigned short* __restrict__ hout){
  int blk = blockIdx.x;
  int n = blk & (N_-1), d = blk >> 9;
  int lane = threadIdx.x;
  int j = lane & 31, hi = lane >> 5;
  float w1[32], w2[32];
  const float* wr1 = whh + (size_t)(d*G_ + lane)*H_;
  const float* wr2 = whh + (size_t)(d*G_ + lane + 64)*H_;
  #pragma unroll
  for (int q = 0; q < 8; ++q){
    float4 aa = *(const float4*)(wr1 + q*4);
    float4 bb = *(const float4*)(wr2 + q*4);
    w1[q*4+0]=aa.x; w1[q*4+1]=aa.y; w1[q*4+2]=aa.z; w1[q*4+3]=aa.w;
    w2[q*4+0]=bb.x; w2[q*4+1]=bb.y; w2[q*4+2]=bb.z; w2[q*4+3]=bb.w;
  }
  const unsigned int* gxu = (const unsigned int*)gx;
  ptrdiff_t stride = d ? -64 : 64;
  const unsigned int* p0 = gxu + ((size_t)(d*N_ + n)*S_ + (d ? (S_-1) : 0))*64 + lane;
  unsigned int buf[8];
  #pragma unroll
  for (int u = 0; u < 8; ++u) buf[u] = p0[stride*u];
  const unsigned int* pf = p0 + stride*8;   // overfetch past chain end stays inside gx buffer

  ptrdiff_t hstride = d ? -64 : 64;
  unsigned short* hop = hout + (size_t)n*S_*64 + (d ? (size_t)(S_-1)*64 : 0) + d*32 + j;

  float hv = 0.f, c = 0.f;
  auto step = [&](unsigned int cur){
    float acc1 = __uint_as_float(cur << 16);          // row lane     (i / f)
    float acc2 = __uint_as_float(cur & 0xffff0000u);  // row lane+64  (g / o)
    float s1 = acc1, s2 = 0.f, s3 = acc2, s4 = 0.f;
    #pragma unroll
    for (int k = 0; k < 32; k += 2){
      float ha = __uint_as_float(__builtin_amdgcn_readlane(__float_as_uint(hv), k));
      float hb = __uint_as_float(__builtin_amdgcn_readlane(__float_as_uint(hv), k+1));
      s1 += ha*w1[k]; s2 += hb*w1[k+1];
      s3 += ha*w2[k]; s4 += hb*w2[k+1];
    }
    acc1 = s1 + s2; acc2 = s3 + s4;
    float a1 = 1.f/(1.f + __expf(-acc1));            // sigmoid (i or f)
    float x2 = hi ? acc2 : 2.f*acc2;                 // shared-exp: o sigm / g tanh
    float tt = 1.f/(1.f + __expf(-x2));
    float a2 = hi ? tt : 2.f*tt - 1.f;
    float b1 = __shfl_xor(a1, 32);
    float b2 = __shfl_xor(a2, 32);
    float i_ = hi ? b1 : a1;
    float f_ = hi ? a1 : b1;
    float g_ = hi ? b2 : a2;
    float o_ = hi ? a2 : b2;
    c = f_*c + i_*g_;
    float tc = 1.f/(1.f + __expf(-2.f*c));
    hv = o_*(2.f*tc - 1.f);
    if (!hi) *hop = bfu(hv);
    hop += hstride;
  };

  for (int ob = 0; ob < 15; ++ob){        // steps 0..119
    #pragma unroll
    for (int u = 0; u < 8; ++u){
      unsigned int cur = buf[u];
      buf[u] = *pf; pf += stride;          // prefetch st+8 (overfetch harmless, never consumed)
      step(cur);
    }
  }
  step(buf[0]);                            // step 120 (loaded at st=112)
}

// ---------------------------------------------------------------- ConvTranspose via MFMA + bias + residual
__global__ __launch_bounds__(256) void k_conv(const unsigned short* __restrict__ hin,
    const unsigned short* __restrict__ wA, const float* __restrict__ bct,
    const float* __restrict__ x, float* __restrict__ out){
  __shared__ unsigned int hraw[S_][33];     // [s][ip] dwords, stride 33 (swizzle for transpose read)
  __shared__ unsigned int hp2[64][144];     // overlapping bf16 pairs [ci][col], col=t'+8, stride 144
  int n = blockIdx.x, b = n >> 7, f = n & 127;
  const unsigned int* hu = (const unsigned int*)hin + (size_t)n*S_*32;
  for (int i = threadIdx.x; i < S_*32; i += 256)
    hraw[i >> 5][i & 31] = hu[i];
  __syncthreads();
  const unsigned short* hr16 = (const unsigned short*)&hraw[0][0];  // u16 idx = s*66 + ci
  for (int it = threadIdx.x; it < 64*136; it += 256){
    int ci = it / 136, col = it - ci*136;
    int t0 = col - 8;
    unsigned int lo  = (t0 >= 0 && t0 < S_)     ? hr16[t0*66 + ci]     : 0u;
    unsigned int hi2 = (t0+1 >= 0 && t0+1 < S_) ? hr16[(t0+1)*66 + ci] : 0u;
    hp2[ci][col] = lo | (hi2 << 16);
  }
  __syncthreads();
  int lane = threadIdx.x & 63, wv = threadIdx.x >> 6;
  int ln = lane & 15, quad = lane >> 4;
  const unsigned short* wp = wA + (size_t)(wv*16 + ln)*512;
  f32x4 acc[8];
  #pragma unroll
  for (int nt = 0; nt < 8; ++nt) acc[nt] = (f32x4){0.f,0.f,0.f,0.f};
  for (int kb = 0; kb < 16; ++kb){
    FragU afr; afr.u = *(const uint4*)(wp + kb*32 + quad*8);
    int ci = kb*4 + quad;
    #pragma unroll
    for (int nt = 0; nt < 8; ++nt){
      FragU bfr;
      const unsigned int* rp = &hp2[ci][nt*16 + ln + 1];
      bfr.u.x = rp[0]; bfr.u.y = rp[2]; bfr.u.z = rp[4]; bfr.u.w = rp[6];
      acc[nt] = __builtin_amdgcn_mfma_f32_16x16x32_bf16(afr.s, bfr.s, acc[nt], 0, 0, 0);
    }
  }
  float bb[4];
  #pragma unroll
  for (int r = 0; r < 4; ++r) bb[r] = bct[wv*16 + quad*4 + r];
  #pragma unroll
  for (int nt = 0; nt < 8; ++nt)
    #pragma unroll
    for (int r = 0; r < 4; ++r){
      int co = wv*16 + quad*4 + r, t = nt*16 + ln;
      size_t idx = ((size_t)(b*64 + co)*128 + f)*128 + t;
      out[idx] = acc[nt][r] + bb[r] + x[idx];
    }
}

// ----------------------------------------------------------------
extern "C" void kernel_launch(void* const* d_in, const int* in_sizes, int n_in,
                              void* d_out, int out_size, void* d_ws, size_t ws_size,
                              hipStream_t stream){
  const float* x     = (const float*)d_in[0];
  const float* gamma = (const float*)d_in[1];
  const float* beta  = (const float*)d_in[2];
  const float* wih0  = (const float*)d_in[3];   // [2,128,512]
  const float* whh0  = (const float*)d_in[4];   // [2,128,32]
  const float* bih0  = (const float*)d_in[5];
  const float* bhh0  = (const float*)d_in[6];
  const float* wih   = (const float*)d_in[7];   // [3,2,128,64]
  const float* whh   = (const float*)d_in[8];   // [3,2,128,32]
  const float* bih   = (const float*)d_in[9];
  const float* bhh   = (const float*)d_in[10];
  const float* wct   = (const float*)d_in[11];  // [64,64,8]
  const float* bct   = (const float*)d_in[12];
  float* out = (float*)d_out;

  char* wsb = (char*)d_ws;
  float*          scale = (float*)(wsb);                       // 1 KB
  float*          shift = (float*)(wsb + 1024);                // 1 KB
  unsigned short* gx    = (unsigned short*)(wsb + 2048);       // 31,719,424 B
  unsigned short* hA    = (unsigned short*)(wsb + 31721472);   // 7,929,856 B
  unsigned short* hB    = (unsigned short*)(wsb + 39651328);   // 7,929,856 B
  unsigned short* wb0   = (unsigned short*)(wsb + 47581184);   // 262,144 B
  unsigned short* wlb   = (unsigned short*)(wsb + 47843328);   // 98,304 B
  unsigned short* wcv   = (unsigned short*)(wsb + 47941632);   // 65,536 B  (~48.0 MB total)

  k_norm<<<256, 256, 0, stream>>>(x, gamma, beta, scale, shift);
  k_wcvt<<<512, 256, 0, stream>>>(wih0, wb0, 2*G_*CK_);
  k_wcvt<<<192, 256, 0, stream>>>(wih,  wlb, 3*2*G_*64);
  k_wrev<<<128, 256, 0, stream>>>(wct,  wcv, 64*512);
  k_gx0 <<<512, 256, 0, stream>>>(x, scale, shift, wb0, bih0, bhh0, gx);
  k_lstm<<<1024, 64, 0, stream>>>(gx, whh0, hA);
  unsigned short* hp = hA; unsigned short* hn = hB;
  for (int l = 0; l < 3; ++l){
    k_gxl <<<512, 256, 0, stream>>>(hp, wlb + (size_t)l*2*G_*64,
                                    bih + (size_t)l*2*G_, bhh + (size_t)l*2*G_, gx);
    k_lstm<<<1024, 64, 0, stream>>>(gx, whh + (size_t)l*2*G_*H_, hn);
    unsigned short* tmp = hp; hp = hn; hn = tmp;
  }
  k_conv<<<512, 256, 0, stream>>>(hp, wcv, bct, x, out);
}